// Round 7
// baseline (242.735 us; speedup 1.0000x reference)
//
#include <hip/hip_runtime.h>
#include <hip/hip_bf16.h>
#include <cstddef>

#define TT 50
#define NN 512
#define DIN 3
#define HH 128
#define NHD 4
#define NPG 64

typedef short short8 __attribute__((ext_vector_type(8)));
typedef float f32x4 __attribute__((ext_vector_type(4)));

// ---- LDS strides (ushort elems) ----
#define SROW 136   // stage rows: 272B, 16B-aligned, 2-way-free banks
#define VROW 56    // Svt rows
#define PROW 72    // P rows
// attn kernel layout
#define SQ_OFF 0
#define SK_OFF 6800
#define SV_OFF 13600
#define PQ_OFF 20784
#define SMEM_E2 39216      // 78,432 B -> 2 blocks/CU
// proj kernel layout: bufA @0, bufB @6800 (+pad for A-frag rows 50..63 reads)
#define SMEM_E1 15504      // 31,008 B -> 5 blocks/CU

static __device__ __forceinline__ unsigned short f2b(float f) {
    unsigned int u = __builtin_bit_cast(unsigned int, f);
    unsigned int r = (u + 0x7fffu + ((u >> 16) & 1u)) >> 16;
    return (unsigned short)r;
}

// Load + convert one wave's 32-out-col fp32 weight tile to bf16 B-fragments.
// Plain loads: with >=5 blocks/CU the TLP hides latency; no asm pinning.
__device__ __forceinline__ void load_conv_w(const float* __restrict__ W,
                                            int nt0, int c, int g,
                                            short8 (&bf)[2][4])
{
#pragma unroll
    for (int i = 0; i < 2; ++i) {
        const float* base = W + (16 * (nt0 + i) + c) * HH + 8 * g;
#pragma unroll
        for (int kb = 0; kb < 4; ++kb) {
            float4 w0 = *reinterpret_cast<const float4*>(base + kb * 32);
            float4 w1 = *reinterpret_cast<const float4*>(base + kb * 32 + 4);
            short8 tt;
            tt[0] = (short)f2b(w0.x); tt[1] = (short)f2b(w0.y);
            tt[2] = (short)f2b(w0.z); tt[3] = (short)f2b(w0.w);
            tt[4] = (short)f2b(w1.x); tt[5] = (short)f2b(w1.y);
            tt[6] = (short)f2b(w1.z); tt[7] = (short)f2b(w1.w);
            bf[i][kb] = tt;
        }
    }
}

// 50x128 @ 128x128 via 16x16x32 bf16 MFMA; A rows from LDS (stride SROW).
__device__ __forceinline__ void gemm_mfma(const unsigned short* __restrict__ sm,
                                          int base, int c, int g,
                                          const short8 (&bf)[2][4], f32x4 (&acc)[4][2])
{
#pragma unroll
    for (int m = 0; m < 4; ++m)
#pragma unroll
        for (int i = 0; i < 2; ++i) acc[m][i] = (f32x4)(0.0f);
#pragma unroll
    for (int kb = 0; kb < 4; ++kb) {
        short8 af[4];
#pragma unroll
        for (int m = 0; m < 4; ++m)
            af[m] = *reinterpret_cast<const short8*>(&sm[base + (16 * m + c) * SROW + kb * 32 + 8 * g]);
#pragma unroll
        for (int m = 0; m < 4; ++m)
#pragma unroll
            for (int i = 0; i < 2; ++i)
                acc[m][i] = __builtin_amdgcn_mfma_f32_16x16x32_bf16(af[m], bf[i][kb], acc[m][i], 0, 0, 0);
    }
}

// ---------------------------------------------------------------------------
// Kernel A0: ego mask -> MF
// ---------------------------------------------------------------------------
__global__ __launch_bounds__(256) void mf_kernel(
    const int* __restrict__ ego, float* __restrict__ MF)
{
    const int idx = blockIdx.x * 256 + threadIdx.x;
    const int t = idx >> 9;
    const int i = idx & 511;
    const int b = i >> 6, p = i & 63;
    MF[idx] = (ego[b * (TT * NPG) + t * NPG + p] != 0) ? 1.0f : 0.0f;
}

// ---------------------------------------------------------------------------
// Kernel A2: edge extraction (row scan + atomic scatter into column lists)
// ---------------------------------------------------------------------------
__global__ __launch_bounds__(256) void edge_kernel(
    const float* __restrict__ adj, const float* __restrict__ MF,
    int* __restrict__ CNT, unsigned short* __restrict__ IDX)
{
    const int bid = blockIdx.x;        // t*16 + chunk
    const int t = bid >> 4;
    const int r0 = (bid & 15) * 32;
    const int tid = threadIdx.x;

    __shared__ float mfS[NN];
    for (int j = tid; j < NN; j += 256) mfS[j] = MF[t * NN + j];
    __syncthreads();

    const int half = tid >> 7;
    const int l = tid & 127;

    for (int rr = 0; rr < 32; rr += 2) {
        const int i = r0 + rr + half;
        if (mfS[i] == 0.0f) continue;
        const float4 a4 = *reinterpret_cast<const float4*>(
            &adj[(size_t)t * NN * NN + (size_t)i * NN + l * 4]);
        const float av[4] = {a4.x, a4.y, a4.z, a4.w};
        const int jbase = l * 4;
#pragma unroll
        for (int u = 0; u < 4; ++u) {
            const int j = jbase + u;
            if (av[u] != 0.0f && mfS[j] != 0.0f) {
                int pos = atomicAdd(&CNT[t * NN + j], 1);
                IDX[((size_t)t * NN + j) * NN + pos] = (unsigned short)i;
            }
        }
    }
}

__global__ __launch_bounds__(256) void dinv_kernel(
    const float* __restrict__ MF, const int* __restrict__ CNT,
    float* __restrict__ DINV)
{
    const int idx = blockIdx.x * 256 + threadIdx.x;
    DINV[idx] = (MF[idx] != 0.0f) ? rsqrtf((float)CNT[idx] + 1.0f) : 0.0f;
}

// ---------------------------------------------------------------------------
// Kernel B: XW1 = (x @ W1) * dinv
// ---------------------------------------------------------------------------
__global__ __launch_bounds__(256) void xw1_kernel(
    const float* __restrict__ x, const float* __restrict__ W1,
    const float* __restrict__ DINV, float* __restrict__ XW)
{
    const int idx = blockIdx.x * 256 + threadIdx.x;
    const int t = idx >> 16;
    const int r = idx & 65535;
    const int i = r >> 7;
    const int f = r & 127;
    const float* xp = x + ((size_t)t * NN + i) * DIN;
    float v = xp[0] * W1[f] + xp[1] * W1[HH + f] + xp[2] * W1[2 * HH + f];
    XW[idx] = v * DINV[t * NN + i];
}

// ---------------------------------------------------------------------------
// Kernel C: column aggregation; optional bf16 output (for EMB), 8-deep ILP
// ---------------------------------------------------------------------------
__global__ __launch_bounds__(128) void agg_kernel(
    const float* __restrict__ XW, const float* __restrict__ MF,
    const float* __restrict__ DINV, const int* __restrict__ CNT,
    const unsigned short* __restrict__ IDX, const float* __restrict__ bias,
    float* __restrict__ OUTF, unsigned short* __restrict__ OUT16, int do_relu)
{
    const int bid = blockIdx.x;
    const int t = bid / NN;
    const int j = bid - t * NN;
    const int f = threadIdx.x;

    __shared__ unsigned short sidx[NN];

    const float mfj = MF[t * NN + j];
    int cnt = 0;
    if (mfj != 0.0f) cnt = CNT[t * NN + j];
    const unsigned short* lst = IDX + ((size_t)t * NN + j) * NN;
    for (int k = f; k < cnt; k += 128) sidx[k] = lst[k];
    __syncthreads();

    float outv = 0.0f;
    if (mfj != 0.0f) {
        const float* base = XW + (size_t)t * NN * HH;
        float a0 = base[j * HH + f], a1 = 0.0f, a2 = 0.0f, a3 = 0.0f;
        float a4 = 0.0f, a5 = 0.0f, a6 = 0.0f, a7 = 0.0f;
        int k = 0;
        for (; k + 8 <= cnt; k += 8) {
            a0 += base[(int)sidx[k]     * HH + f];
            a1 += base[(int)sidx[k + 1] * HH + f];
            a2 += base[(int)sidx[k + 2] * HH + f];
            a3 += base[(int)sidx[k + 3] * HH + f];
            a4 += base[(int)sidx[k + 4] * HH + f];
            a5 += base[(int)sidx[k + 5] * HH + f];
            a6 += base[(int)sidx[k + 6] * HH + f];
            a7 += base[(int)sidx[k + 7] * HH + f];
        }
        for (; k + 2 <= cnt; k += 2) {
            a0 += base[(int)sidx[k]     * HH + f];
            a1 += base[(int)sidx[k + 1] * HH + f];
        }
        if (k < cnt) a2 += base[(int)sidx[k] * HH + f];
        outv = DINV[t * NN + j] * (((a0 + a1) + (a2 + a3)) + ((a4 + a5) + (a6 + a7))) + bias[f];
        if (do_relu) outv = fmaxf(outv, 0.0f);
    }
    if (OUT16) OUT16[(size_t)t * NN * HH + j * HH + f] = f2b(outv);
    else       OUTF[(size_t)t * NN * HH + j * HH + f] = outv;
}

// ---------------------------------------------------------------------------
// Kernel D: XW2 = (H1 @ W2) * dinv
// ---------------------------------------------------------------------------
__global__ __launch_bounds__(128) void xw2_kernel(
    const float* __restrict__ Hin, const float* __restrict__ W2,
    const float* __restrict__ DINV, float* __restrict__ XW2)
{
    const int bid = blockIdx.x;
    const int t = bid >> 4;
    const int chunk = bid & 15;
    const int f = threadIdx.x;

    __shared__ float W2S[HH * HH];
    __shared__ float rowsS[32 * HH];

    for (int idx = f; idx < HH * HH; idx += 128) W2S[idx] = W2[idx];
    const float* hb = Hin + (size_t)t * NN * HH + (size_t)chunk * 32 * HH;
    for (int idx = f; idx < 32 * HH; idx += 128) rowsS[idx] = hb[idx];
    __syncthreads();

    float acc[32];
#pragma unroll
    for (int r = 0; r < 32; ++r) acc[r] = 0.0f;

    for (int h = 0; h < HH; ++h) {
        float w = W2S[h * HH + f];
#pragma unroll
        for (int r = 0; r < 32; ++r) acc[r] = fmaf(rowsS[r * HH + h], w, acc[r]);
    }

    float* ob = XW2 + (size_t)t * NN * HH + (size_t)chunk * 32 * HH;
    const float* dv = DINV + t * NN + chunk * 32;
#pragma unroll
    for (int r = 0; r < 32; ++r) ob[r * HH + f] = acc[r] * dv[r];
}

// ---------------------------------------------------------------------------
// Kernel E1: per-(node, s in {q,k,v}) chained projection pair.
// GEMM1: emb @ Ws^T + bs -> bufB; GEMM2: bufB @ Win_s^T + bin_s (scale s=0)
// -> QKVH bf16. 1536 blocks, 31 KB LDS -> 5 blocks/CU (20 waves/CU TLP).
// ---------------------------------------------------------------------------
__global__ __launch_bounds__(256) void proj_kernel(
    const unsigned short* __restrict__ EMB16,
    const float* __restrict__ Wq, const float* __restrict__ bq,
    const float* __restrict__ Wk, const float* __restrict__ bk,
    const float* __restrict__ Wv, const float* __restrict__ bv,
    const float* __restrict__ W_in, const float* __restrict__ b_in,
    unsigned short* __restrict__ QKVH)
{
    __shared__ unsigned short sm[SMEM_E1];
    const int bid = blockIdx.x;
    const int n = bid / 3;
    const int s = bid - 3 * n;
    const int tid = threadIdx.x;
    const int lane = tid & 63;
    const int wid = tid >> 6;
    const int g = lane >> 4, c = lane & 15;
    const int nt0 = 2 * wid;

    const size_t nHH = (size_t)n * HH * HH;
    const size_t n3HH = (size_t)n * 3 * HH * HH;

    const float *Wa, *ba, *Wb, *bb;
    if (s == 0)      { Wa = Wq + nHH; ba = bq + (size_t)n * HH;
                       Wb = W_in + n3HH;               bb = b_in + (size_t)n * 3 * HH; }
    else if (s == 1) { Wa = Wk + nHH; ba = bk + (size_t)n * HH;
                       Wb = W_in + n3HH + HH * HH;     bb = b_in + (size_t)n * 3 * HH + HH; }
    else             { Wa = Wv + nHH; ba = bv + (size_t)n * HH;
                       Wb = W_in + n3HH + 2 * HH * HH; bb = b_in + (size_t)n * 3 * HH + 2 * HH; }

    const float ba0 = ba[16 * nt0 + c], ba1 = ba[16 * nt0 + 16 + c];
    const float bb0 = bb[16 * nt0 + c], bb1 = bb[16 * nt0 + 16 + c];

    // stage emb (bf16) into bufA
    for (int idx = tid; idx < TT * (HH / 8); idx += 256) {
        int t = idx >> 4, h8 = (idx & 15) * 8;
        *reinterpret_cast<short8*>(&sm[t * SROW + h8]) =
            *reinterpret_cast<const short8*>(&EMB16[((size_t)t * NN + n) * HH + h8]);
    }
    __syncthreads();

    // GEMM1
    short8 bfA[2][4];
    load_conv_w(Wa, nt0, c, g, bfA);
    f32x4 acc[4][2];
    gemm_mfma(sm, 0, c, g, bfA, acc);
    __syncthreads();   // all bufA reads done before bufB writes (regions abut)
#pragma unroll
    for (int m = 0; m < 4; ++m)
#pragma unroll
        for (int i = 0; i < 2; ++i)
#pragma unroll
            for (int r = 0; r < 4; ++r) {
                const int row = 16 * m + 4 * g + r;
                if (row >= TT) continue;
                sm[6800 + row * SROW + 16 * (nt0 + i) + c] = f2b(acc[m][i][r] + (i ? ba1 : ba0));
            }
    __syncthreads();

    // GEMM2
    short8 bfB[2][4];
    load_conv_w(Wb, nt0, c, g, bfB);
    gemm_mfma(sm, 6800, c, g, bfB, acc);

    constexpr float scale = 0.17677669529663687f;  // 1/sqrt(32)
    unsigned short* gout = QKVH + (size_t)(n * 3 + s) * (TT * HH);
#pragma unroll
    for (int m = 0; m < 4; ++m)
#pragma unroll
        for (int i = 0; i < 2; ++i)
#pragma unroll
            for (int r = 0; r < 4; ++r) {
                const int row = 16 * m + 4 * g + r;
                if (row >= TT) continue;
                float v = acc[m][i][r] + (i ? bb1 : bb0);
                if (s == 0) v *= scale;
                gout[row * HH + 16 * (nt0 + i) + c] = f2b(v);
            }
}

// ---------------------------------------------------------------------------
// Kernel E2: per-node MHA + out_proj (wave = head).
// ---------------------------------------------------------------------------
__global__ __launch_bounds__(256) void attn_kernel(
    const unsigned short* __restrict__ QKVH,
    const float* __restrict__ W_out, const float* __restrict__ b_out,
    float* __restrict__ out)
{
    __shared__ unsigned short sm[SMEM_E2];
    const int n = blockIdx.x;
    const int tid = threadIdx.x;
    const int lane = tid & 63;
    const int wid = tid >> 6;
    const int g = lane >> 4, c = lane & 15;
    const int nt0 = 2 * wid;

    // zero Svt tail: cols 50..55 of each of 128 rows + 16-elem pad past row 127
    // (PV reads k=0..63; unwritten LDS could decode as NaN and NaN*0 poisons O)
    for (int idx = tid; idx < HH * 6 + 16; idx += 256) {
        if (idx < HH * 6) {
            int d = idx / 6, cc = idx - d * 6;
            sm[SV_OFF + d * VROW + TT + cc] = 0;
        } else {
            sm[SV_OFF + HH * VROW + (idx - HH * 6)] = 0;
        }
    }

    const unsigned short* q16 = QKVH + (size_t)n * 3 * (TT * HH);
    // stage Sq, Sk rows
    for (int idx = tid; idx < TT * (HH / 8); idx += 256) {
        int t = idx >> 4, h8 = (idx & 15) * 8;
        *reinterpret_cast<short8*>(&sm[SQ_OFF + t * SROW + h8]) =
            *reinterpret_cast<const short8*>(&q16[t * HH + h8]);
        *reinterpret_cast<short8*>(&sm[SK_OFF + t * SROW + h8]) =
            *reinterpret_cast<const short8*>(&q16[TT * HH + t * HH + h8]);
    }
    // stage Svt transposed (scalar LDS writes)
    for (int idx = tid; idx < TT * (HH / 8); idx += 256) {
        int t = idx >> 4, d8 = (idx & 15) * 8;
        short8 v = *reinterpret_cast<const short8*>(&q16[2 * TT * HH + t * HH + d8]);
#pragma unroll
        for (int u = 0; u < 8; ++u)
            sm[SV_OFF + (d8 + u) * VROW + t] = (unsigned short)v[u];
    }
    __syncthreads();

    const int hd = wid;

    // QK^T
    f32x4 sacc[4][4];
#pragma unroll
    for (int m = 0; m < 4; ++m)
#pragma unroll
        for (int j = 0; j < 4; ++j) sacc[m][j] = (f32x4)(0.0f);

    short8 aq[4], bk8[4];
#pragma unroll
    for (int m = 0; m < 4; ++m)
        aq[m] = *reinterpret_cast<const short8*>(&sm[SQ_OFF + (16 * m + c) * SROW + hd * 32 + 8 * g]);
#pragma unroll
    for (int j = 0; j < 4; ++j)
        bk8[j] = *reinterpret_cast<const short8*>(&sm[SK_OFF + (16 * j + c) * SROW + hd * 32 + 8 * g]);
#pragma unroll
    for (int m = 0; m < 4; ++m)
#pragma unroll
        for (int j = 0; j < 4; ++j)
            sacc[m][j] = __builtin_amdgcn_mfma_f32_16x16x32_bf16(aq[m], bk8[j], sacc[m][j], 0, 0, 0);

    // softmax -> normalized P (bf16) in LDS
    const bool mask3 = (c >= 2);
    unsigned short* Pbase = &sm[PQ_OFF + hd * 64 * PROW];
#pragma unroll
    for (int m = 0; m < 4; ++m)
#pragma unroll
        for (int r = 0; r < 4; ++r) {
            float v0 = sacc[m][0][r], v1 = sacc[m][1][r], v2 = sacc[m][2][r];
            float v3 = mask3 ? -3.0e38f : sacc[m][3][r];
            float mx = fmaxf(fmaxf(v0, v1), fmaxf(v2, v3));
            mx = fmaxf(mx, __shfl_xor(mx, 1, 16));
            mx = fmaxf(mx, __shfl_xor(mx, 2, 16));
            mx = fmaxf(mx, __shfl_xor(mx, 4, 16));
            mx = fmaxf(mx, __shfl_xor(mx, 8, 16));
            float e0 = __expf(v0 - mx), e1 = __expf(v1 - mx), e2 = __expf(v2 - mx);
            float e3 = mask3 ? 0.0f : __expf(v3 - mx);
            float sum_ = e0 + e1 + e2 + e3;
            sum_ += __shfl_xor(sum_, 1, 16);
            sum_ += __shfl_xor(sum_, 2, 16);
            sum_ += __shfl_xor(sum_, 4, 16);
            sum_ += __shfl_xor(sum_, 8, 16);
            float inv = 1.0f / sum_;
            const int q = 16 * m + 4 * g + r;
            unsigned short* pr = Pbase + q * PROW;
            pr[c]      = f2b(e0 * inv);
            pr[16 + c] = f2b(e1 * inv);
            pr[32 + c] = f2b(e2 * inv);
            pr[48 + c] = f2b(e3 * inv);
        }
    __syncthreads();

    // PV
    f32x4 pacc[2][4];
#pragma unroll
    for (int mtd = 0; mtd < 2; ++mtd)
#pragma unroll
        for (int ntq = 0; ntq < 4; ++ntq) pacc[mtd][ntq] = (f32x4)(0.0f);

#pragma unroll
    for (int kb = 0; kb < 2; ++kb) {
        short8 av[2], bp[4];
#pragma unroll
        for (int mtd = 0; mtd < 2; ++mtd)
            av[mtd] = *reinterpret_cast<const short8*>(&sm[SV_OFF + (hd * 32 + 16 * mtd + c) * VROW + kb * 32 + 8 * g]);
#pragma unroll
        for (int ntq = 0; ntq < 4; ++ntq)
            bp[ntq] = *reinterpret_cast<const short8*>(&sm[PQ_OFF + hd * 64 * PROW + (16 * ntq + c) * PROW + kb * 32 + 8 * g]);
#pragma unroll
        for (int mtd = 0; mtd < 2; ++mtd)
#pragma unroll
            for (int ntq = 0; ntq < 4; ++ntq)
                pacc[mtd][ntq] = __builtin_amdgcn_mfma_f32_16x16x32_bf16(av[mtd], bp[ntq], pacc[mtd][ntq], 0, 0, 0);
    }

    // O -> SQ region (dead)
#pragma unroll
    for (int mtd = 0; mtd < 2; ++mtd)
#pragma unroll
        for (int ntq = 0; ntq < 4; ++ntq)
#pragma unroll
            for (int r = 0; r < 4; ++r) {
                const int q = 16 * ntq + c;
                if (q < TT)
                    sm[SQ_OFF + q * SROW + hd * 32 + 16 * mtd + 4 * g + r] = f2b(pacc[mtd][ntq][r]);
            }
    __syncthreads();

    // out_proj
    short8 bfO[2][4];
    load_conv_w(W_out + (size_t)n * HH * HH, nt0, c, g, bfO);
    f32x4 acc[4][2];
    gemm_mfma(sm, SQ_OFF, c, g, bfO, acc);

    const float bo0 = b_out[(size_t)n * HH + 16 * nt0 + c];
    const float bo1 = b_out[(size_t)n * HH + 16 * nt0 + 16 + c];
    float* outp = out + (size_t)n * (TT * HH);
#pragma unroll
    for (int m = 0; m < 4; ++m)
#pragma unroll
        for (int i = 0; i < 2; ++i)
#pragma unroll
            for (int r = 0; r < 4; ++r) {
                const int row = 16 * m + 4 * g + r;
                if (row >= TT) continue;
                outp[row * HH + 16 * (nt0 + i) + c] = acc[m][i][r] + (i ? bo1 : bo0);
            }
}

// ---------------------------------------------------------------------------
extern "C" void kernel_launch(void* const* d_in, const int* in_sizes, int n_in,
                              void* d_out, int out_size, void* d_ws, size_t ws_size,
                              hipStream_t stream)
{
    const float* x     = (const float*)d_in[0];
    const float* adj   = (const float*)d_in[1];
    const int*   ego   = (const int*)d_in[2];
    const float* W1    = (const float*)d_in[3];
    const float* b1    = (const float*)d_in[4];
    const float* W2    = (const float*)d_in[5];
    const float* b2    = (const float*)d_in[6];
    const float* Wq    = (const float*)d_in[7];
    const float* bq    = (const float*)d_in[8];
    const float* Wk    = (const float*)d_in[9];
    const float* bk    = (const float*)d_in[10];
    const float* Wv    = (const float*)d_in[11];
    const float* bv    = (const float*)d_in[12];
    const float* W_in  = (const float*)d_in[13];
    const float* b_in  = (const float*)d_in[14];
    const float* W_out = (const float*)d_in[15];
    const float* b_out = (const float*)d_in[16];
    float* out = (float*)d_out;

    char* ws = (char*)d_ws;
    float*          MF    = (float*)(ws + 0);
    float*          DINV  = (float*)(ws + 102400);
    int*            CNT   = (int*)(ws + 204800);
    unsigned short* IDX   = (unsigned short*)(ws + 307200);       // 26,214,400 B
    unsigned short* QKVH  = (unsigned short*)(ws + 26521600);     // 19,660,800 B (overlays XW+H1, dead by proj launch)
    float*          XW    = (float*)(ws + 26521600);              // 13,107,200 B
    float*          H1    = (float*)(ws + 39628800);              // 13,107,200 B
    unsigned short* EMB16 = (unsigned short*)(ws + 52736000);     //  6,553,600 B

    hipMemsetAsync(CNT, 0, TT * NN * sizeof(int), stream);
    mf_kernel<<<dim3(100), dim3(256), 0, stream>>>(ego, MF);
    edge_kernel<<<dim3(TT * 16), dim3(256), 0, stream>>>(adj, MF, CNT, IDX);
    dinv_kernel<<<dim3(100), dim3(256), 0, stream>>>(MF, CNT, DINV);
    xw1_kernel<<<dim3(12800), dim3(256), 0, stream>>>(x, W1, DINV, XW);
    agg_kernel<<<dim3(TT * NN), dim3(128), 0, stream>>>(XW, MF, DINV, CNT, IDX, b1, H1, nullptr, 1);
    xw2_kernel<<<dim3(TT * 16), dim3(128), 0, stream>>>(H1, W2, DINV, XW);
    agg_kernel<<<dim3(TT * NN), dim3(128), 0, stream>>>(XW, MF, DINV, CNT, IDX, b2, nullptr, EMB16, 0);
    proj_kernel<<<dim3(NN * 3), dim3(256), 0, stream>>>(EMB16, Wq, bq, Wk, bk, Wv, bv,
                                                        W_in, b_in, QKVH);
    attn_kernel<<<dim3(NN), dim3(256), 0, stream>>>(QKVH, W_out, b_out, out);
}

// Round 8
// 238.574 us; speedup vs baseline: 1.0174x; 1.0174x over previous
//
#include <hip/hip_runtime.h>
#include <hip/hip_bf16.h>
#include <cstddef>

#define TT 50
#define NN 512
#define DIN 3
#define HH 128
#define NHD 4
#define NPG 64

typedef short short8 __attribute__((ext_vector_type(8)));
typedef float f32x4 __attribute__((ext_vector_type(4)));

// ---- LDS strides (ushort elems) ----
#define SROW 136   // stage rows: 272B, 16B-aligned, 2-way-free banks
#define VROW 56    // Svt rows
#define PROW 72    // P rows
// attn kernel layout
#define SQ_OFF 0
#define SK_OFF 6800
#define SV_OFF 13600
#define PQ_OFF 20784
#define SMEM_E2 39216      // 78,432 B -> 2 blocks/CU
// proj kernel layout: bufA @0, bufB @6800
#define SMEM_E1 15504      // 31,008 B; residency thread-capped: 4 blocks/CU @512thr

static __device__ __forceinline__ unsigned short f2b(float f) {
    unsigned int u = __builtin_bit_cast(unsigned int, f);
    unsigned int r = (u + 0x7fffu + ((u >> 16) & 1u)) >> 16;
    return (unsigned short)r;
}
static __device__ __forceinline__ float b2f(unsigned short h) {
    unsigned int u = ((unsigned int)h) << 16;
    return __builtin_bit_cast(float, u);
}

// ---------------------------------------------------------------------------
// Kernel A0: ego mask -> MF
// ---------------------------------------------------------------------------
__global__ __launch_bounds__(256) void mf_kernel(
    const int* __restrict__ ego, float* __restrict__ MF)
{
    const int idx = blockIdx.x * 256 + threadIdx.x;
    const int t = idx >> 9;
    const int i = idx & 511;
    const int b = i >> 6, p = i & 63;
    MF[idx] = (ego[b * (TT * NPG) + t * NPG + p] != 0) ? 1.0f : 0.0f;
}

// ---------------------------------------------------------------------------
// Kernel A2: edge extraction (row scan + atomic scatter into column lists)
// ---------------------------------------------------------------------------
__global__ __launch_bounds__(256) void edge_kernel(
    const float* __restrict__ adj, const float* __restrict__ MF,
    int* __restrict__ CNT, unsigned short* __restrict__ IDX)
{
    const int bid = blockIdx.x;        // t*16 + chunk
    const int t = bid >> 4;
    const int r0 = (bid & 15) * 32;
    const int tid = threadIdx.x;

    __shared__ float mfS[NN];
    for (int j = tid; j < NN; j += 256) mfS[j] = MF[t * NN + j];
    __syncthreads();

    const int half = tid >> 7;
    const int l = tid & 127;

    for (int rr = 0; rr < 32; rr += 2) {
        const int i = r0 + rr + half;
        if (mfS[i] == 0.0f) continue;
        const float4 a4 = *reinterpret_cast<const float4*>(
            &adj[(size_t)t * NN * NN + (size_t)i * NN + l * 4]);
        const float av[4] = {a4.x, a4.y, a4.z, a4.w};
        const int jbase = l * 4;
#pragma unroll
        for (int u = 0; u < 4; ++u) {
            const int j = jbase + u;
            if (av[u] != 0.0f && mfS[j] != 0.0f) {
                int pos = atomicAdd(&CNT[t * NN + j], 1);
                IDX[((size_t)t * NN + j) * NN + pos] = (unsigned short)i;
            }
        }
    }
}

__global__ __launch_bounds__(256) void dinv_kernel(
    const float* __restrict__ MF, const int* __restrict__ CNT,
    float* __restrict__ DINV)
{
    const int idx = blockIdx.x * 256 + threadIdx.x;
    DINV[idx] = (MF[idx] != 0.0f) ? rsqrtf((float)CNT[idx] + 1.0f) : 0.0f;
}

// ---------------------------------------------------------------------------
// Kernel B: XW1 = (x @ W1) * dinv  -> bf16
// ---------------------------------------------------------------------------
__global__ __launch_bounds__(256) void xw1_kernel(
    const float* __restrict__ x, const float* __restrict__ W1,
    const float* __restrict__ DINV, unsigned short* __restrict__ XW16)
{
    const int idx = blockIdx.x * 256 + threadIdx.x;
    const int t = idx >> 16;
    const int r = idx & 65535;
    const int i = r >> 7;
    const int f = r & 127;
    const float* xp = x + ((size_t)t * NN + i) * DIN;
    float v = xp[0] * W1[f] + xp[1] * W1[HH + f] + xp[2] * W1[2 * HH + f];
    XW16[idx] = f2b(v * DINV[t * NN + i]);
}

// ---------------------------------------------------------------------------
// Kernel C: column aggregation from bf16 XW (fp32 accumulate), bf16 output
// ---------------------------------------------------------------------------
__global__ __launch_bounds__(128) void agg_kernel(
    const unsigned short* __restrict__ XW16, const float* __restrict__ MF,
    const float* __restrict__ DINV, const int* __restrict__ CNT,
    const unsigned short* __restrict__ IDX, const float* __restrict__ bias,
    unsigned short* __restrict__ OUT16, int do_relu)
{
    const int bid = blockIdx.x;
    const int t = bid / NN;
    const int j = bid - t * NN;
    const int f = threadIdx.x;

    __shared__ unsigned short sidx[NN];

    const float mfj = MF[t * NN + j];
    int cnt = 0;
    if (mfj != 0.0f) cnt = CNT[t * NN + j];
    const unsigned short* lst = IDX + ((size_t)t * NN + j) * NN;
    for (int k = f; k < cnt; k += 128) sidx[k] = lst[k];
    __syncthreads();

    float outv = 0.0f;
    if (mfj != 0.0f) {
        const unsigned short* base = XW16 + (size_t)t * NN * HH;
        float a0 = b2f(base[j * HH + f]), a1 = 0.0f, a2 = 0.0f, a3 = 0.0f;
        float a4 = 0.0f, a5 = 0.0f, a6 = 0.0f, a7 = 0.0f;
        int k = 0;
        for (; k + 8 <= cnt; k += 8) {
            a0 += b2f(base[(int)sidx[k]     * HH + f]);
            a1 += b2f(base[(int)sidx[k + 1] * HH + f]);
            a2 += b2f(base[(int)sidx[k + 2] * HH + f]);
            a3 += b2f(base[(int)sidx[k + 3] * HH + f]);
            a4 += b2f(base[(int)sidx[k + 4] * HH + f]);
            a5 += b2f(base[(int)sidx[k + 5] * HH + f]);
            a6 += b2f(base[(int)sidx[k + 6] * HH + f]);
            a7 += b2f(base[(int)sidx[k + 7] * HH + f]);
        }
        for (; k + 2 <= cnt; k += 2) {
            a0 += b2f(base[(int)sidx[k]     * HH + f]);
            a1 += b2f(base[(int)sidx[k + 1] * HH + f]);
        }
        if (k < cnt) a2 += b2f(base[(int)sidx[k] * HH + f]);
        outv = DINV[t * NN + j] * (((a0 + a1) + (a2 + a3)) + ((a4 + a5) + (a6 + a7))) + bias[f];
        if (do_relu) outv = fmaxf(outv, 0.0f);
    }
    OUT16[(size_t)t * NN * HH + j * HH + f] = f2b(outv);
}

// ---------------------------------------------------------------------------
// Kernel D: XW2 = (H1 @ W2) * dinv ; H1 bf16 in, bf16 out, fp32 compute
// ---------------------------------------------------------------------------
__global__ __launch_bounds__(128) void xw2_kernel(
    const unsigned short* __restrict__ H16, const float* __restrict__ W2,
    const float* __restrict__ DINV, unsigned short* __restrict__ XW16)
{
    const int bid = blockIdx.x;
    const int t = bid >> 4;
    const int chunk = bid & 15;
    const int f = threadIdx.x;

    __shared__ float W2S[HH * HH];
    __shared__ float rowsS[32 * HH];

    for (int idx = f; idx < HH * HH; idx += 128) W2S[idx] = W2[idx];
    const unsigned short* hb = H16 + (size_t)t * NN * HH + (size_t)chunk * 32 * HH;
    for (int idx = f; idx < (32 * HH) / 8; idx += 128) {
        short8 v = *reinterpret_cast<const short8*>(&hb[idx * 8]);
#pragma unroll
        for (int u = 0; u < 8; ++u) rowsS[idx * 8 + u] = b2f((unsigned short)v[u]);
    }
    __syncthreads();

    float acc[32];
#pragma unroll
    for (int r = 0; r < 32; ++r) acc[r] = 0.0f;

    for (int h = 0; h < HH; ++h) {
        float w = W2S[h * HH + f];
#pragma unroll
        for (int r = 0; r < 32; ++r) acc[r] = fmaf(rowsS[r * HH + h], w, acc[r]);
    }

    unsigned short* ob = XW16 + (size_t)t * NN * HH + (size_t)chunk * 32 * HH;
    const float* dv = DINV + t * NN + chunk * 32;
#pragma unroll
    for (int r = 0; r < 32; ++r) ob[r * HH + f] = f2b(acc[r] * dv[r]);
}

// ---------------------------------------------------------------------------
// Kernel E1: per-(node, s) chained projection pair. 512 threads / 8 waves,
// each wave owns ONE 16-col output tile -> 8 independent short load bursts,
// 4 blocks/CU = 32 waves/CU (occupancy-driven streaming).
// ---------------------------------------------------------------------------
__global__ __launch_bounds__(512) void proj_kernel(
    const unsigned short* __restrict__ EMB16,
    const float* __restrict__ Wq, const float* __restrict__ bq,
    const float* __restrict__ Wk, const float* __restrict__ bk,
    const float* __restrict__ Wv, const float* __restrict__ bv,
    const float* __restrict__ W_in, const float* __restrict__ b_in,
    unsigned short* __restrict__ QKVH)
{
    __shared__ unsigned short sm[SMEM_E1];
    const int bid = blockIdx.x;
    const int n = bid / 3;
    const int s = bid - 3 * n;
    const int tid = threadIdx.x;
    const int lane = tid & 63;
    const int wid = tid >> 6;          // 0..7 -> output cols [16*wid, 16*wid+16)
    const int g = lane >> 4, c = lane & 15;

    const size_t nHH = (size_t)n * HH * HH;
    const size_t n3HH = (size_t)n * 3 * HH * HH;

    const float *Wa, *ba, *Wb, *bb;
    if (s == 0)      { Wa = Wq + nHH; ba = bq + (size_t)n * HH;
                       Wb = W_in + n3HH;               bb = b_in + (size_t)n * 3 * HH; }
    else if (s == 1) { Wa = Wk + nHH; ba = bk + (size_t)n * HH;
                       Wb = W_in + n3HH + HH * HH;     bb = b_in + (size_t)n * 3 * HH + HH; }
    else             { Wa = Wv + nHH; ba = bv + (size_t)n * HH;
                       Wb = W_in + n3HH + 2 * HH * HH; bb = b_in + (size_t)n * 3 * HH + 2 * HH; }

    const int col = 16 * wid + c;
    const float bav = ba[col];
    const float bbv = bb[col];

    // stage emb (bf16) into bufA
    for (int idx = tid; idx < TT * (HH / 8); idx += 512) {
        int t = idx >> 4, h8 = (idx & 15) * 8;
        *reinterpret_cast<short8*>(&sm[t * SROW + h8]) =
            *reinterpret_cast<const short8*>(&EMB16[((size_t)t * NN + n) * HH + h8]);
    }
    __syncthreads();

    // ---- GEMM1: load wave's 16-row fp32 weight tile (8 dwordx4), convert ----
    short8 bfA[4];
    {
        const float* basep = Wa + col * HH + 8 * g;
#pragma unroll
        for (int kb = 0; kb < 4; ++kb) {
            float4 w0 = *reinterpret_cast<const float4*>(basep + kb * 32);
            float4 w1 = *reinterpret_cast<const float4*>(basep + kb * 32 + 4);
            short8 tt;
            tt[0] = (short)f2b(w0.x); tt[1] = (short)f2b(w0.y);
            tt[2] = (short)f2b(w0.z); tt[3] = (short)f2b(w0.w);
            tt[4] = (short)f2b(w1.x); tt[5] = (short)f2b(w1.y);
            tt[6] = (short)f2b(w1.z); tt[7] = (short)f2b(w1.w);
            bfA[kb] = tt;
        }
    }
    f32x4 acc[4];
#pragma unroll
    for (int m = 0; m < 4; ++m) acc[m] = (f32x4)(0.0f);
#pragma unroll
    for (int kb = 0; kb < 4; ++kb) {
        short8 af[4];
#pragma unroll
        for (int m = 0; m < 4; ++m)
            af[m] = *reinterpret_cast<const short8*>(&sm[(16 * m + c) * SROW + kb * 32 + 8 * g]);
#pragma unroll
        for (int m = 0; m < 4; ++m)
            acc[m] = __builtin_amdgcn_mfma_f32_16x16x32_bf16(af[m], bfA[kb], acc[m], 0, 0, 0);
    }
    __syncthreads();   // bufA reads done
#pragma unroll
    for (int m = 0; m < 4; ++m)
#pragma unroll
        for (int r = 0; r < 4; ++r) {
            const int row = 16 * m + 4 * g + r;
            if (row >= TT) continue;
            sm[6800 + row * SROW + col] = f2b(acc[m][r] + bav);
        }
    __syncthreads();

    // ---- GEMM2 ----
    short8 bfB[4];
    {
        const float* basep = Wb + col * HH + 8 * g;
#pragma unroll
        for (int kb = 0; kb < 4; ++kb) {
            float4 w0 = *reinterpret_cast<const float4*>(basep + kb * 32);
            float4 w1 = *reinterpret_cast<const float4*>(basep + kb * 32 + 4);
            short8 tt;
            tt[0] = (short)f2b(w0.x); tt[1] = (short)f2b(w0.y);
            tt[2] = (short)f2b(w0.z); tt[3] = (short)f2b(w0.w);
            tt[4] = (short)f2b(w1.x); tt[5] = (short)f2b(w1.y);
            tt[6] = (short)f2b(w1.z); tt[7] = (short)f2b(w1.w);
            bfB[kb] = tt;
        }
    }
#pragma unroll
    for (int m = 0; m < 4; ++m) acc[m] = (f32x4)(0.0f);
#pragma unroll
    for (int kb = 0; kb < 4; ++kb) {
        short8 af[4];
#pragma unroll
        for (int m = 0; m < 4; ++m)
            af[m] = *reinterpret_cast<const short8*>(&sm[6800 + (16 * m + c) * SROW + kb * 32 + 8 * g]);
#pragma unroll
        for (int m = 0; m < 4; ++m)
            acc[m] = __builtin_amdgcn_mfma_f32_16x16x32_bf16(af[m], bfB[kb], acc[m], 0, 0, 0);
    }

    constexpr float scale = 0.17677669529663687f;  // 1/sqrt(32)
    unsigned short* gout = QKVH + (size_t)(n * 3 + s) * (TT * HH);
#pragma unroll
    for (int m = 0; m < 4; ++m)
#pragma unroll
        for (int r = 0; r < 4; ++r) {
            const int row = 16 * m + 4 * g + r;
            if (row >= TT) continue;
            float v = acc[m][r] + bbv;
            if (s == 0) v *= scale;
            gout[row * HH + col] = f2b(v);
        }
}

// ---------------------------------------------------------------------------
// Kernel E2: per-node MHA + out_proj (wave = head). Unchanged from R7.
// ---------------------------------------------------------------------------
__global__ __launch_bounds__(256) void attn_kernel(
    const unsigned short* __restrict__ QKVH,
    const float* __restrict__ W_out, const float* __restrict__ b_out,
    float* __restrict__ out)
{
    __shared__ unsigned short sm[SMEM_E2];
    const int n = blockIdx.x;
    const int tid = threadIdx.x;
    const int lane = tid & 63;
    const int wid = tid >> 6;
    const int g = lane >> 4, c = lane & 15;
    const int nt0 = 2 * wid;

    // zero Svt tail (cols 50..55 each row + pad past row 127)
    for (int idx = tid; idx < HH * 6 + 16; idx += 256) {
        if (idx < HH * 6) {
            int d = idx / 6, cc = idx - d * 6;
            sm[SV_OFF + d * VROW + TT + cc] = 0;
        } else {
            sm[SV_OFF + HH * VROW + (idx - HH * 6)] = 0;
        }
    }

    const unsigned short* q16 = QKVH + (size_t)n * 3 * (TT * HH);
    for (int idx = tid; idx < TT * (HH / 8); idx += 256) {
        int t = idx >> 4, h8 = (idx & 15) * 8;
        *reinterpret_cast<short8*>(&sm[SQ_OFF + t * SROW + h8]) =
            *reinterpret_cast<const short8*>(&q16[t * HH + h8]);
        *reinterpret_cast<short8*>(&sm[SK_OFF + t * SROW + h8]) =
            *reinterpret_cast<const short8*>(&q16[TT * HH + t * HH + h8]);
    }
    for (int idx = tid; idx < TT * (HH / 8); idx += 256) {
        int t = idx >> 4, d8 = (idx & 15) * 8;
        short8 v = *reinterpret_cast<const short8*>(&q16[2 * TT * HH + t * HH + d8]);
#pragma unroll
        for (int u = 0; u < 8; ++u)
            sm[SV_OFF + (d8 + u) * VROW + t] = (unsigned short)v[u];
    }
    __syncthreads();

    const int hd = wid;

    f32x4 sacc[4][4];
#pragma unroll
    for (int m = 0; m < 4; ++m)
#pragma unroll
        for (int j = 0; j < 4; ++j) sacc[m][j] = (f32x4)(0.0f);

    short8 aq[4], bk8[4];
#pragma unroll
    for (int m = 0; m < 4; ++m)
        aq[m] = *reinterpret_cast<const short8*>(&sm[SQ_OFF + (16 * m + c) * SROW + hd * 32 + 8 * g]);
#pragma unroll
    for (int j = 0; j < 4; ++j)
        bk8[j] = *reinterpret_cast<const short8*>(&sm[SK_OFF + (16 * j + c) * SROW + hd * 32 + 8 * g]);
#pragma unroll
    for (int m = 0; m < 4; ++m)
#pragma unroll
        for (int j = 0; j < 4; ++j)
            sacc[m][j] = __builtin_amdgcn_mfma_f32_16x16x32_bf16(aq[m], bk8[j], sacc[m][j], 0, 0, 0);

    const bool mask3 = (c >= 2);
    unsigned short* Pbase = &sm[PQ_OFF + hd * 64 * PROW];
#pragma unroll
    for (int m = 0; m < 4; ++m)
#pragma unroll
        for (int r = 0; r < 4; ++r) {
            float v0 = sacc[m][0][r], v1 = sacc[m][1][r], v2 = sacc[m][2][r];
            float v3 = mask3 ? -3.0e38f : sacc[m][3][r];
            float mx = fmaxf(fmaxf(v0, v1), fmaxf(v2, v3));
            mx = fmaxf(mx, __shfl_xor(mx, 1, 16));
            mx = fmaxf(mx, __shfl_xor(mx, 2, 16));
            mx = fmaxf(mx, __shfl_xor(mx, 4, 16));
            mx = fmaxf(mx, __shfl_xor(mx, 8, 16));
            float e0 = __expf(v0 - mx), e1 = __expf(v1 - mx), e2 = __expf(v2 - mx);
            float e3 = mask3 ? 0.0f : __expf(v3 - mx);
            float sum_ = e0 + e1 + e2 + e3;
            sum_ += __shfl_xor(sum_, 1, 16);
            sum_ += __shfl_xor(sum_, 2, 16);
            sum_ += __shfl_xor(sum_, 4, 16);
            sum_ += __shfl_xor(sum_, 8, 16);
            float inv = 1.0f / sum_;
            const int q = 16 * m + 4 * g + r;
            unsigned short* pr = Pbase + q * PROW;
            pr[c]      = f2b(e0 * inv);
            pr[16 + c] = f2b(e1 * inv);
            pr[32 + c] = f2b(e2 * inv);
            pr[48 + c] = f2b(e3 * inv);
        }
    __syncthreads();

    f32x4 pacc[2][4];
#pragma unroll
    for (int mtd = 0; mtd < 2; ++mtd)
#pragma unroll
        for (int ntq = 0; ntq < 4; ++ntq) pacc[mtd][ntq] = (f32x4)(0.0f);

#pragma unroll
    for (int kb = 0; kb < 2; ++kb) {
        short8 av[2], bp[4];
#pragma unroll
        for (int mtd = 0; mtd < 2; ++mtd)
            av[mtd] = *reinterpret_cast<const short8*>(&sm[SV_OFF + (hd * 32 + 16 * mtd + c) * VROW + kb * 32 + 8 * g]);
#pragma unroll
        for (int ntq = 0; ntq < 4; ++ntq)
            bp[ntq] = *reinterpret_cast<const short8*>(&sm[PQ_OFF + hd * 64 * PROW + (16 * ntq + c) * PROW + kb * 32 + 8 * g]);
#pragma unroll
        for (int mtd = 0; mtd < 2; ++mtd)
#pragma unroll
            for (int ntq = 0; ntq < 4; ++ntq)
                pacc[mtd][ntq] = __builtin_amdgcn_mfma_f32_16x16x32_bf16(av[mtd], bp[ntq], pacc[mtd][ntq], 0, 0, 0);
    }

#pragma unroll
    for (int mtd = 0; mtd < 2; ++mtd)
#pragma unroll
        for (int ntq = 0; ntq < 4; ++ntq)
#pragma unroll
            for (int r = 0; r < 4; ++r) {
                const int q = 16 * ntq + c;
                if (q < TT)
                    sm[SQ_OFF + q * SROW + hd * 32 + 16 * mtd + 4 * g + r] = f2b(pacc[mtd][ntq][r]);
            }
    __syncthreads();

    // out_proj
    short8 bfO[2][4];
#pragma unroll
    for (int i = 0; i < 2; ++i) {
        const float* basep = W_out + (size_t)n * HH * HH + (16 * (nt0 + i) + c) * HH + 8 * g;
#pragma unroll
        for (int kb = 0; kb < 4; ++kb) {
            float4 w0 = *reinterpret_cast<const float4*>(basep + kb * 32);
            float4 w1 = *reinterpret_cast<const float4*>(basep + kb * 32 + 4);
            short8 tt;
            tt[0] = (short)f2b(w0.x); tt[1] = (short)f2b(w0.y);
            tt[2] = (short)f2b(w0.z); tt[3] = (short)f2b(w0.w);
            tt[4] = (short)f2b(w1.x); tt[5] = (short)f2b(w1.y);
            tt[6] = (short)f2b(w1.z); tt[7] = (short)f2b(w1.w);
            bfO[i][kb] = tt;
        }
    }
    f32x4 acc[4][2];
#pragma unroll
    for (int m = 0; m < 4; ++m)
#pragma unroll
        for (int i = 0; i < 2; ++i) acc[m][i] = (f32x4)(0.0f);
#pragma unroll
    for (int kb = 0; kb < 4; ++kb) {
        short8 af[4];
#pragma unroll
        for (int m = 0; m < 4; ++m)
            af[m] = *reinterpret_cast<const short8*>(&sm[SQ_OFF + (16 * m + c) * SROW + kb * 32 + 8 * g]);
#pragma unroll
        for (int m = 0; m < 4; ++m)
#pragma unroll
            for (int i = 0; i < 2; ++i)
                acc[m][i] = __builtin_amdgcn_mfma_f32_16x16x32_bf16(af[m], bfO[i][kb], acc[m][i], 0, 0, 0);
    }

    const float bo0 = b_out[(size_t)n * HH + 16 * nt0 + c];
    const float bo1 = b_out[(size_t)n * HH + 16 * nt0 + 16 + c];
    float* outp = out + (size_t)n * (TT * HH);
#pragma unroll
    for (int m = 0; m < 4; ++m)
#pragma unroll
        for (int i = 0; i < 2; ++i)
#pragma unroll
            for (int r = 0; r < 4; ++r) {
                const int row = 16 * m + 4 * g + r;
                if (row >= TT) continue;
                outp[row * HH + 16 * (nt0 + i) + c] = acc[m][i][r] + (i ? bo1 : bo0);
            }
}

// ---------------------------------------------------------------------------
extern "C" void kernel_launch(void* const* d_in, const int* in_sizes, int n_in,
                              void* d_out, int out_size, void* d_ws, size_t ws_size,
                              hipStream_t stream)
{
    const float* x     = (const float*)d_in[0];
    const float* adj   = (const float*)d_in[1];
    const int*   ego   = (const int*)d_in[2];
    const float* W1    = (const float*)d_in[3];
    const float* b1    = (const float*)d_in[4];
    const float* W2    = (const float*)d_in[5];
    const float* b2    = (const float*)d_in[6];
    const float* Wq    = (const float*)d_in[7];
    const float* bq    = (const float*)d_in[8];
    const float* Wk    = (const float*)d_in[9];
    const float* bk    = (const float*)d_in[10];
    const float* Wv    = (const float*)d_in[11];
    const float* bv    = (const float*)d_in[12];
    const float* W_in  = (const float*)d_in[13];
    const float* b_in  = (const float*)d_in[14];
    const float* W_out = (const float*)d_in[15];
    const float* b_out = (const float*)d_in[16];
    float* out = (float*)d_out;

    char* ws = (char*)d_ws;
    float*          MF    = (float*)(ws + 0);
    float*          DINV  = (float*)(ws + 102400);
    int*            CNT   = (int*)(ws + 204800);
    unsigned short* IDX   = (unsigned short*)(ws + 307200);       // 26,214,400 B
    unsigned short* QKVH  = (unsigned short*)(ws + 26521600);     // 19,660,800 B
    unsigned short* XW16  = (unsigned short*)(ws + 46182400);     //  6,553,600 B
    unsigned short* H16   = (unsigned short*)(ws + 52736000);     //  6,553,600 B
    unsigned short* EMB16 = (unsigned short*)(ws + 59289600);     //  6,553,600 B

    hipMemsetAsync(CNT, 0, TT * NN * sizeof(int), stream);
    mf_kernel<<<dim3(100), dim3(256), 0, stream>>>(ego, MF);
    edge_kernel<<<dim3(TT * 16), dim3(256), 0, stream>>>(adj, MF, CNT, IDX);
    dinv_kernel<<<dim3(100), dim3(256), 0, stream>>>(MF, CNT, DINV);
    xw1_kernel<<<dim3(12800), dim3(256), 0, stream>>>(x, W1, DINV, XW16);
    agg_kernel<<<dim3(TT * NN), dim3(128), 0, stream>>>(XW16, MF, DINV, CNT, IDX, b1, H16, 1);
    xw2_kernel<<<dim3(TT * 16), dim3(128), 0, stream>>>(H16, W2, DINV, XW16);
    agg_kernel<<<dim3(TT * NN), dim3(128), 0, stream>>>(XW16, MF, DINV, CNT, IDX, b2, EMB16, 0);
    proj_kernel<<<dim3(NN * 3), dim3(512), 0, stream>>>(EMB16, Wq, bq, Wk, bk, Wv, bv,
                                                        W_in, b_in, QKVH);
    attn_kernel<<<dim3(NN), dim3(256), 0, stream>>>(QKVH, W_out, b_out, out);
}

// Round 9
// 174.926 us; speedup vs baseline: 1.3876x; 1.3639x over previous
//
#include <hip/hip_runtime.h>
#include <hip/hip_bf16.h>
#include <cstddef>

#define TT 50
#define NN 512
#define DIN 3
#define HH 128
#define NHD 4
#define NPG 64

typedef short short8 __attribute__((ext_vector_type(8)));
typedef float f32x4 __attribute__((ext_vector_type(4)));

// ---- LDS strides (ushort elems) ----
#define SROW 136   // stage rows: 272B, 16B-aligned
#define VROW 56    // Svt rows
#define PROW 72    // P rows
// attn kernel layout
#define SQ_OFF 0
#define SK_OFF 6800
#define SV_OFF 13600
#define PQ_OFF 20784
#define SMEM_E2 39216      // 78,432 B -> 2 blocks/CU
// proj kernel layout: bufA @0 (50x136 + overread pad), bufB @6800 (+pad), W @15504
#define PB_OFF 6800
#define PW_OFF 15504
#define SMEM_E1 32912      // 65,824 B -> 2 blocks/CU @512thr
// xw2 layout: H rows @0, W2^T @17408
#define XW_WOFF 17408
#define SMEM_X 34816       // 69,632 B -> 2 blocks/CU

static __device__ __forceinline__ unsigned short f2b(float f) {
    unsigned int u = __builtin_bit_cast(unsigned int, f);
    unsigned int r = (u + 0x7fffu + ((u >> 16) & 1u)) >> 16;
    return (unsigned short)r;
}
static __device__ __forceinline__ float b2f(unsigned short h) {
    unsigned int u = ((unsigned int)h) << 16;
    return __builtin_bit_cast(float, u);
}

// ---------------------------------------------------------------------------
// Kernel A0: ego mask -> MF
// ---------------------------------------------------------------------------
__global__ __launch_bounds__(256) void mf_kernel(
    const int* __restrict__ ego, float* __restrict__ MF)
{
    const int idx = blockIdx.x * 256 + threadIdx.x;
    const int t = idx >> 9;
    const int i = idx & 511;
    const int b = i >> 6, p = i & 63;
    MF[idx] = (ego[b * (TT * NPG) + t * NPG + p] != 0) ? 1.0f : 0.0f;
}

// ---------------------------------------------------------------------------
// Kernel A2: edge extraction (row scan + atomic scatter into column lists)
// ---------------------------------------------------------------------------
__global__ __launch_bounds__(256) void edge_kernel(
    const float* __restrict__ adj, const float* __restrict__ MF,
    int* __restrict__ CNT, unsigned short* __restrict__ IDX)
{
    const int bid = blockIdx.x;        // t*16 + chunk
    const int t = bid >> 4;
    const int r0 = (bid & 15) * 32;
    const int tid = threadIdx.x;

    __shared__ float mfS[NN];
    for (int j = tid; j < NN; j += 256) mfS[j] = MF[t * NN + j];
    __syncthreads();

    const int half = tid >> 7;
    const int l = tid & 127;

    for (int rr = 0; rr < 32; rr += 2) {
        const int i = r0 + rr + half;
        if (mfS[i] == 0.0f) continue;
        const float4 a4 = *reinterpret_cast<const float4*>(
            &adj[(size_t)t * NN * NN + (size_t)i * NN + l * 4]);
        const float av[4] = {a4.x, a4.y, a4.z, a4.w};
        const int jbase = l * 4;
#pragma unroll
        for (int u = 0; u < 4; ++u) {
            const int j = jbase + u;
            if (av[u] != 0.0f && mfS[j] != 0.0f) {
                int pos = atomicAdd(&CNT[t * NN + j], 1);
                IDX[((size_t)t * NN + j) * NN + pos] = (unsigned short)i;
            }
        }
    }
}

__global__ __launch_bounds__(256) void dinv_kernel(
    const float* __restrict__ MF, const int* __restrict__ CNT,
    float* __restrict__ DINV)
{
    const int idx = blockIdx.x * 256 + threadIdx.x;
    DINV[idx] = (MF[idx] != 0.0f) ? rsqrtf((float)CNT[idx] + 1.0f) : 0.0f;
}

// ---------------------------------------------------------------------------
// Kernel B: XW1 = (x @ W1) * dinv  -> bf16
// ---------------------------------------------------------------------------
__global__ __launch_bounds__(256) void xw1_kernel(
    const float* __restrict__ x, const float* __restrict__ W1,
    const float* __restrict__ DINV, unsigned short* __restrict__ XW16)
{
    const int idx = blockIdx.x * 256 + threadIdx.x;
    const int t = idx >> 16;
    const int r = idx & 65535;
    const int i = r >> 7;
    const int f = r & 127;
    const float* xp = x + ((size_t)t * NN + i) * DIN;
    float v = xp[0] * W1[f] + xp[1] * W1[HH + f] + xp[2] * W1[2 * HH + f];
    XW16[idx] = f2b(v * DINV[t * NN + i]);
}

// ---------------------------------------------------------------------------
// Kernel C: column aggregation from bf16 XW (fp32 accumulate), bf16 output
// ---------------------------------------------------------------------------
__global__ __launch_bounds__(128) void agg_kernel(
    const unsigned short* __restrict__ XW16, const float* __restrict__ MF,
    const float* __restrict__ DINV, const int* __restrict__ CNT,
    const unsigned short* __restrict__ IDX, const float* __restrict__ bias,
    unsigned short* __restrict__ OUT16, int do_relu)
{
    const int bid = blockIdx.x;
    const int t = bid / NN;
    const int j = bid - t * NN;
    const int f = threadIdx.x;

    __shared__ unsigned short sidx[NN];

    const float mfj = MF[t * NN + j];
    int cnt = 0;
    if (mfj != 0.0f) cnt = CNT[t * NN + j];
    const unsigned short* lst = IDX + ((size_t)t * NN + j) * NN;
    for (int k = f; k < cnt; k += 128) sidx[k] = lst[k];
    __syncthreads();

    float outv = 0.0f;
    if (mfj != 0.0f) {
        const unsigned short* base = XW16 + (size_t)t * NN * HH;
        float a0 = b2f(base[j * HH + f]), a1 = 0.0f, a2 = 0.0f, a3 = 0.0f;
        float a4 = 0.0f, a5 = 0.0f, a6 = 0.0f, a7 = 0.0f;
        int k = 0;
        for (; k + 8 <= cnt; k += 8) {
            a0 += b2f(base[(int)sidx[k]     * HH + f]);
            a1 += b2f(base[(int)sidx[k + 1] * HH + f]);
            a2 += b2f(base[(int)sidx[k + 2] * HH + f]);
            a3 += b2f(base[(int)sidx[k + 3] * HH + f]);
            a4 += b2f(base[(int)sidx[k + 4] * HH + f]);
            a5 += b2f(base[(int)sidx[k + 5] * HH + f]);
            a6 += b2f(base[(int)sidx[k + 6] * HH + f]);
            a7 += b2f(base[(int)sidx[k + 7] * HH + f]);
        }
        for (; k + 2 <= cnt; k += 2) {
            a0 += b2f(base[(int)sidx[k]     * HH + f]);
            a1 += b2f(base[(int)sidx[k + 1] * HH + f]);
        }
        if (k < cnt) a2 += b2f(base[(int)sidx[k] * HH + f]);
        outv = DINV[t * NN + j] * (((a0 + a1) + (a2 + a3)) + ((a4 + a5) + (a6 + a7))) + bias[f];
        if (do_relu) outv = fmaxf(outv, 0.0f);
    }
    OUT16[(size_t)t * NN * HH + j * HH + f] = f2b(outv);
}

// ---------------------------------------------------------------------------
// Kernel D (MFMA): XW2 = (H @ W2) * dinv on flat [25600][128].
// 200 blocks x 256 thr (4 waves, 2 n-tiles each). H rows + W2^T staged in LDS.
// ---------------------------------------------------------------------------
__global__ __launch_bounds__(256) void xw2_kernel(
    const unsigned short* __restrict__ H16, const float* __restrict__ W2,
    const float* __restrict__ DINV, unsigned short* __restrict__ XW16)
{
    __shared__ unsigned short sm[SMEM_X];
    const int r0 = blockIdx.x * 128;
    const int tid = threadIdx.x;
    const int lane = tid & 63;
    const int wid = tid >> 6;
    const int g = lane >> 4, c = lane & 15;
    const int nt0 = 2 * wid;

    // stage 128 H rows (bf16, coalesced)
#pragma unroll
    for (int it = 0; it < 8; ++it) {
        const int idx = it * 256 + tid;            // short8 chunks
        const int row = idx >> 4, h8 = (idx & 15) * 8;
        *reinterpret_cast<short8*>(&sm[row * SROW + h8]) =
            *reinterpret_cast<const short8*>(&H16[(size_t)(r0 + row) * HH + h8]);
    }
    // stage W2 (fp32 [h][f]) transposed -> WT[f][h] bf16
#pragma unroll
    for (int it = 0; it < 16; ++it) {
        const int flat = it * 1024 + tid * 4;
        float4 w = *reinterpret_cast<const float4*>(W2 + flat);
        const int h = flat >> 7, f0 = flat & 127;
        sm[XW_WOFF + (f0 + 0) * SROW + h] = f2b(w.x);
        sm[XW_WOFF + (f0 + 1) * SROW + h] = f2b(w.y);
        sm[XW_WOFF + (f0 + 2) * SROW + h] = f2b(w.z);
        sm[XW_WOFF + (f0 + 3) * SROW + h] = f2b(w.w);
    }
    __syncthreads();

    f32x4 acc[8][2];
#pragma unroll
    for (int m = 0; m < 8; ++m)
#pragma unroll
        for (int i = 0; i < 2; ++i) acc[m][i] = (f32x4)(0.0f);

#pragma unroll
    for (int kb = 0; kb < 4; ++kb) {
        short8 bf[2];
#pragma unroll
        for (int i = 0; i < 2; ++i)
            bf[i] = *reinterpret_cast<const short8*>(
                &sm[XW_WOFF + (16 * (nt0 + i) + c) * SROW + kb * 32 + 8 * g]);
#pragma unroll
        for (int m = 0; m < 8; ++m) {
            short8 af = *reinterpret_cast<const short8*>(
                &sm[(16 * m + c) * SROW + kb * 32 + 8 * g]);
#pragma unroll
            for (int i = 0; i < 2; ++i)
                acc[m][i] = __builtin_amdgcn_mfma_f32_16x16x32_bf16(af, bf[i], acc[m][i], 0, 0, 0);
        }
    }

#pragma unroll
    for (int m = 0; m < 8; ++m)
#pragma unroll
        for (int r = 0; r < 4; ++r) {
            const int row = 16 * m + 4 * g + r;
            const float dv = DINV[r0 + row];
#pragma unroll
            for (int i = 0; i < 2; ++i)
                XW16[(size_t)(r0 + row) * HH + 16 * (nt0 + i) + c] = f2b(acc[m][i][r] * dv);
        }
}

// ---------------------------------------------------------------------------
// Kernel E1: per-(node, s) chained projection pair; weights staged through LDS
// with COALESCED fp32 loads (16B/lane contiguous), bf16-converted on store.
// 512 thr / 8 waves, wave owns one 16-col tile. 2 blocks/CU.
// ---------------------------------------------------------------------------
__global__ __launch_bounds__(512) void proj_kernel(
    const unsigned short* __restrict__ EMB16,
    const float* __restrict__ Wq, const float* __restrict__ bq,
    const float* __restrict__ Wk, const float* __restrict__ bk,
    const float* __restrict__ Wv, const float* __restrict__ bv,
    const float* __restrict__ W_in, const float* __restrict__ b_in,
    unsigned short* __restrict__ QKVH)
{
    __shared__ unsigned short sm[SMEM_E1];
    const int bid = blockIdx.x;
    const int n = bid / 3;
    const int s = bid - 3 * n;
    const int tid = threadIdx.x;
    const int lane = tid & 63;
    const int wid = tid >> 6;          // 0..7 -> output cols [16*wid, +16)
    const int g = lane >> 4, c = lane & 15;

    const size_t nHH = (size_t)n * HH * HH;
    const size_t n3HH = (size_t)n * 3 * HH * HH;

    const float *Wa, *ba, *Wb, *bb;
    if (s == 0)      { Wa = Wq + nHH; ba = bq + (size_t)n * HH;
                       Wb = W_in + n3HH;               bb = b_in + (size_t)n * 3 * HH; }
    else if (s == 1) { Wa = Wk + nHH; ba = bk + (size_t)n * HH;
                       Wb = W_in + n3HH + HH * HH;     bb = b_in + (size_t)n * 3 * HH + HH; }
    else             { Wa = Wv + nHH; ba = bv + (size_t)n * HH;
                       Wb = W_in + n3HH + 2 * HH * HH; bb = b_in + (size_t)n * 3 * HH + 2 * HH; }

    const int col = 16 * wid + c;
    const float bav = ba[col];
    const float bbv = bb[col];

    // stage emb (bf16) into bufA; stage Wa (coalesced, fp32->bf16) into W buf
    for (int idx = tid; idx < TT * (HH / 8); idx += 512) {
        int t = idx >> 4, h8 = (idx & 15) * 8;
        *reinterpret_cast<short8*>(&sm[t * SROW + h8]) =
            *reinterpret_cast<const short8*>(&EMB16[((size_t)t * NN + n) * HH + h8]);
    }
#pragma unroll
    for (int it = 0; it < 8; ++it) {
        const int flat = it * 2048 + tid * 4;       // 512 thr x float4
        float4 w = *reinterpret_cast<const float4*>(Wa + flat);
        const int row = flat >> 7, cw = flat & 127;
        unsigned short* p = &sm[PW_OFF + row * SROW + cw];
        p[0] = f2b(w.x); p[1] = f2b(w.y); p[2] = f2b(w.z); p[3] = f2b(w.w);
    }
    __syncthreads();

    // ---- GEMM1: B-frags from LDS W buf ----
    f32x4 acc[4];
#pragma unroll
    for (int m = 0; m < 4; ++m) acc[m] = (f32x4)(0.0f);
#pragma unroll
    for (int kb = 0; kb < 4; ++kb) {
        short8 bf = *reinterpret_cast<const short8*>(
            &sm[PW_OFF + col * SROW + kb * 32 + 8 * g]);
#pragma unroll
        for (int m = 0; m < 4; ++m) {
            short8 af = *reinterpret_cast<const short8*>(
                &sm[(16 * m + c) * SROW + kb * 32 + 8 * g]);
            acc[m] = __builtin_amdgcn_mfma_f32_16x16x32_bf16(af, bf, acc[m], 0, 0, 0);
        }
    }
    __syncthreads();   // bufA + W-buf reads done

    // write GEMM1 out -> bufB ; stage Wb into W buf
#pragma unroll
    for (int m = 0; m < 4; ++m)
#pragma unroll
        for (int r = 0; r < 4; ++r) {
            const int row = 16 * m + 4 * g + r;
            if (row >= TT) continue;
            sm[PB_OFF + row * SROW + col] = f2b(acc[m][r] + bav);
        }
#pragma unroll
    for (int it = 0; it < 8; ++it) {
        const int flat = it * 2048 + tid * 4;
        float4 w = *reinterpret_cast<const float4*>(Wb + flat);
        const int row = flat >> 7, cw = flat & 127;
        unsigned short* p = &sm[PW_OFF + row * SROW + cw];
        p[0] = f2b(w.x); p[1] = f2b(w.y); p[2] = f2b(w.z); p[3] = f2b(w.w);
    }
    __syncthreads();

    // ---- GEMM2 ----
#pragma unroll
    for (int m = 0; m < 4; ++m) acc[m] = (f32x4)(0.0f);
#pragma unroll
    for (int kb = 0; kb < 4; ++kb) {
        short8 bf = *reinterpret_cast<const short8*>(
            &sm[PW_OFF + col * SROW + kb * 32 + 8 * g]);
#pragma unroll
        for (int m = 0; m < 4; ++m) {
            short8 af = *reinterpret_cast<const short8*>(
                &sm[PB_OFF + (16 * m + c) * SROW + kb * 32 + 8 * g]);
            acc[m] = __builtin_amdgcn_mfma_f32_16x16x32_bf16(af, bf, acc[m], 0, 0, 0);
        }
    }

    constexpr float scale = 0.17677669529663687f;  // 1/sqrt(32)
    unsigned short* gout = QKVH + (size_t)(n * 3 + s) * (TT * HH);
#pragma unroll
    for (int m = 0; m < 4; ++m)
#pragma unroll
        for (int r = 0; r < 4; ++r) {
            const int row = 16 * m + 4 * g + r;
            if (row >= TT) continue;
            float v = acc[m][r] + bbv;
            if (s == 0) v *= scale;
            gout[row * HH + col] = f2b(v);
        }
}

// ---------------------------------------------------------------------------
// Kernel E2: per-node MHA + out_proj (wave = head).
// ---------------------------------------------------------------------------
__global__ __launch_bounds__(256) void attn_kernel(
    const unsigned short* __restrict__ QKVH,
    const float* __restrict__ W_out, const float* __restrict__ b_out,
    float* __restrict__ out)
{
    __shared__ unsigned short sm[SMEM_E2];
    const int n = blockIdx.x;
    const int tid = threadIdx.x;
    const int lane = tid & 63;
    const int wid = tid >> 6;
    const int g = lane >> 4, c = lane & 15;
    const int nt0 = 2 * wid;

    // zero Svt tail (cols 50..55 each row + pad past row 127)
    for (int idx = tid; idx < HH * 6 + 16; idx += 256) {
        if (idx < HH * 6) {
            int d = idx / 6, cc = idx - d * 6;
            sm[SV_OFF + d * VROW + TT + cc] = 0;
        } else {
            sm[SV_OFF + HH * VROW + (idx - HH * 6)] = 0;
        }
    }

    const unsigned short* q16 = QKVH + (size_t)n * 3 * (TT * HH);
    for (int idx = tid; idx < TT * (HH / 8); idx += 256) {
        int t = idx >> 4, h8 = (idx & 15) * 8;
        *reinterpret_cast<short8*>(&sm[SQ_OFF + t * SROW + h8]) =
            *reinterpret_cast<const short8*>(&q16[t * HH + h8]);
        *reinterpret_cast<short8*>(&sm[SK_OFF + t * SROW + h8]) =
            *reinterpret_cast<const short8*>(&q16[TT * HH + t * HH + h8]);
    }
    for (int idx = tid; idx < TT * (HH / 8); idx += 256) {
        int t = idx >> 4, d8 = (idx & 15) * 8;
        short8 v = *reinterpret_cast<const short8*>(&q16[2 * TT * HH + t * HH + d8]);
#pragma unroll
        for (int u = 0; u < 8; ++u)
            sm[SV_OFF + (d8 + u) * VROW + t] = (unsigned short)v[u];
    }
    __syncthreads();

    const int hd = wid;

    f32x4 sacc[4][4];
#pragma unroll
    for (int m = 0; m < 4; ++m)
#pragma unroll
        for (int j = 0; j < 4; ++j) sacc[m][j] = (f32x4)(0.0f);

    short8 aq[4], bk8[4];
#pragma unroll
    for (int m = 0; m < 4; ++m)
        aq[m] = *reinterpret_cast<const short8*>(&sm[SQ_OFF + (16 * m + c) * SROW + hd * 32 + 8 * g]);
#pragma unroll
    for (int j = 0; j < 4; ++j)
        bk8[j] = *reinterpret_cast<const short8*>(&sm[SK_OFF + (16 * j + c) * SROW + hd * 32 + 8 * g]);
#pragma unroll
    for (int m = 0; m < 4; ++m)
#pragma unroll
        for (int j = 0; j < 4; ++j)
            sacc[m][j] = __builtin_amdgcn_mfma_f32_16x16x32_bf16(aq[m], bk8[j], sacc[m][j], 0, 0, 0);

    const bool mask3 = (c >= 2);
    unsigned short* Pbase = &sm[PQ_OFF + hd * 64 * PROW];
#pragma unroll
    for (int m = 0; m < 4; ++m)
#pragma unroll
        for (int r = 0; r < 4; ++r) {
            float v0 = sacc[m][0][r], v1 = sacc[m][1][r], v2 = sacc[m][2][r];
            float v3 = mask3 ? -3.0e38f : sacc[m][3][r];
            float mx = fmaxf(fmaxf(v0, v1), fmaxf(v2, v3));
            mx = fmaxf(mx, __shfl_xor(mx, 1, 16));
            mx = fmaxf(mx, __shfl_xor(mx, 2, 16));
            mx = fmaxf(mx, __shfl_xor(mx, 4, 16));
            mx = fmaxf(mx, __shfl_xor(mx, 8, 16));
            float e0 = __expf(v0 - mx), e1 = __expf(v1 - mx), e2 = __expf(v2 - mx);
            float e3 = mask3 ? 0.0f : __expf(v3 - mx);
            float sum_ = e0 + e1 + e2 + e3;
            sum_ += __shfl_xor(sum_, 1, 16);
            sum_ += __shfl_xor(sum_, 2, 16);
            sum_ += __shfl_xor(sum_, 4, 16);
            sum_ += __shfl_xor(sum_, 8, 16);
            float inv = 1.0f / sum_;
            const int q = 16 * m + 4 * g + r;
            unsigned short* pr = Pbase + q * PROW;
            pr[c]      = f2b(e0 * inv);
            pr[16 + c] = f2b(e1 * inv);
            pr[32 + c] = f2b(e2 * inv);
            pr[48 + c] = f2b(e3 * inv);
        }
    __syncthreads();

    f32x4 pacc[2][4];
#pragma unroll
    for (int mtd = 0; mtd < 2; ++mtd)
#pragma unroll
        for (int ntq = 0; ntq < 4; ++ntq) pacc[mtd][ntq] = (f32x4)(0.0f);

#pragma unroll
    for (int kb = 0; kb < 2; ++kb) {
        short8 av[2], bp[4];
#pragma unroll
        for (int mtd = 0; mtd < 2; ++mtd)
            av[mtd] = *reinterpret_cast<const short8*>(&sm[SV_OFF + (hd * 32 + 16 * mtd + c) * VROW + kb * 32 + 8 * g]);
#pragma unroll
        for (int ntq = 0; ntq < 4; ++ntq)
            bp[ntq] = *reinterpret_cast<const short8*>(&sm[PQ_OFF + hd * 64 * PROW + (16 * ntq + c) * PROW + kb * 32 + 8 * g]);
#pragma unroll
        for (int mtd = 0; mtd < 2; ++mtd)
#pragma unroll
            for (int ntq = 0; ntq < 4; ++ntq)
                pacc[mtd][ntq] = __builtin_amdgcn_mfma_f32_16x16x32_bf16(av[mtd], bp[ntq], pacc[mtd][ntq], 0, 0, 0);
    }

#pragma unroll
    for (int mtd = 0; mtd < 2; ++mtd)
#pragma unroll
        for (int ntq = 0; ntq < 4; ++ntq)
#pragma unroll
            for (int r = 0; r < 4; ++r) {
                const int q = 16 * ntq + c;
                if (q < TT)
                    sm[SQ_OFF + q * SROW + hd * 32 + 16 * mtd + 4 * g + r] = f2b(pacc[mtd][ntq][r]);
            }
    __syncthreads();

    // out_proj
    short8 bfO[2][4];
#pragma unroll
    for (int i = 0; i < 2; ++i) {
        const float* basep = W_out + (size_t)n * HH * HH + (16 * (nt0 + i) + c) * HH + 8 * g;
#pragma unroll
        for (int kb = 0; kb < 4; ++kb) {
            float4 w0 = *reinterpret_cast<const float4*>(basep + kb * 32);
            float4 w1 = *reinterpret_cast<const float4*>(basep + kb * 32 + 4);
            short8 tt;
            tt[0] = (short)f2b(w0.x); tt[1] = (short)f2b(w0.y);
            tt[2] = (short)f2b(w0.z); tt[3] = (short)f2b(w0.w);
            tt[4] = (short)f2b(w1.x); tt[5] = (short)f2b(w1.y);
            tt[6] = (short)f2b(w1.z); tt[7] = (short)f2b(w1.w);
            bfO[i][kb] = tt;
        }
    }
    f32x4 acc[4][2];
#pragma unroll
    for (int m = 0; m < 4; ++m)
#pragma unroll
        for (int i = 0; i < 2; ++i) acc[m][i] = (f32x4)(0.0f);
#pragma unroll
    for (int kb = 0; kb < 4; ++kb) {
        short8 af[4];
#pragma unroll
        for (int m = 0; m < 4; ++m)
            af[m] = *reinterpret_cast<const short8*>(&sm[SQ_OFF + (16 * m + c) * SROW + kb * 32 + 8 * g]);
#pragma unroll
        for (int m = 0; m < 4; ++m)
#pragma unroll
            for (int i = 0; i < 2; ++i)
                acc[m][i] = __builtin_amdgcn_mfma_f32_16x16x32_bf16(af[m], bfO[i][kb], acc[m][i], 0, 0, 0);
    }

    const float bo0 = b_out[(size_t)n * HH + 16 * nt0 + c];
    const float bo1 = b_out[(size_t)n * HH + 16 * nt0 + 16 + c];
    float* outp = out + (size_t)n * (TT * HH);
#pragma unroll
    for (int m = 0; m < 4; ++m)
#pragma unroll
        for (int i = 0; i < 2; ++i)
#pragma unroll
            for (int r = 0; r < 4; ++r) {
                const int row = 16 * m + 4 * g + r;
                if (row >= TT) continue;
                outp[row * HH + 16 * (nt0 + i) + c] = acc[m][i][r] + (i ? bo1 : bo0);
            }
}

// ---------------------------------------------------------------------------
extern "C" void kernel_launch(void* const* d_in, const int* in_sizes, int n_in,
                              void* d_out, int out_size, void* d_ws, size_t ws_size,
                              hipStream_t stream)
{
    const float* x     = (const float*)d_in[0];
    const float* adj   = (const float*)d_in[1];
    const int*   ego   = (const int*)d_in[2];
    const float* W1    = (const float*)d_in[3];
    const float* b1    = (const float*)d_in[4];
    const float* W2    = (const float*)d_in[5];
    const float* b2    = (const float*)d_in[6];
    const float* Wq    = (const float*)d_in[7];
    const float* bq    = (const float*)d_in[8];
    const float* Wk    = (const float*)d_in[9];
    const float* bk    = (const float*)d_in[10];
    const float* Wv    = (const float*)d_in[11];
    const float* bv    = (const float*)d_in[12];
    const float* W_in  = (const float*)d_in[13];
    const float* b_in  = (const float*)d_in[14];
    const float* W_out = (const float*)d_in[15];
    const float* b_out = (const float*)d_in[16];
    float* out = (float*)d_out;

    char* ws = (char*)d_ws;
    float*          MF    = (float*)(ws + 0);
    float*          DINV  = (float*)(ws + 102400);
    int*            CNT   = (int*)(ws + 204800);
    unsigned short* IDX   = (unsigned short*)(ws + 307200);       // 26,214,400 B
    unsigned short* QKVH  = (unsigned short*)(ws + 26521600);     // 19,660,800 B
    unsigned short* XW16  = (unsigned short*)(ws + 46182400);     //  6,553,600 B
    unsigned short* H16   = (unsigned short*)(ws + 52736000);     //  6,553,600 B
    unsigned short* EMB16 = (unsigned short*)(ws + 59289600);     //  6,553,600 B

    hipMemsetAsync(CNT, 0, TT * NN * sizeof(int), stream);
    mf_kernel<<<dim3(100), dim3(256), 0, stream>>>(ego, MF);
    edge_kernel<<<dim3(TT * 16), dim3(256), 0, stream>>>(adj, MF, CNT, IDX);
    dinv_kernel<<<dim3(100), dim3(256), 0, stream>>>(MF, CNT, DINV);
    xw1_kernel<<<dim3(12800), dim3(256), 0, stream>>>(x, W1, DINV, XW16);
    agg_kernel<<<dim3(TT * NN), dim3(128), 0, stream>>>(XW16, MF, DINV, CNT, IDX, b1, H16, 1);
    xw2_kernel<<<dim3(200), dim3(256), 0, stream>>>(H16, W2, DINV, XW16);
    agg_kernel<<<dim3(TT * NN), dim3(128), 0, stream>>>(XW16, MF, DINV, CNT, IDX, b2, EMB16, 0);
    proj_kernel<<<dim3(NN * 3), dim3(512), 0, stream>>>(EMB16, Wq, bq, Wk, bk, Wv, bv,
                                                        W_in, b_in, QKVH);
    attn_kernel<<<dim3(NN), dim3(256), 0, stream>>>(QKVH, W_out, b_out, out);
}